// Round 6
// baseline (2756.345 us; speedup 1.0000x reference)
//
#include <hip/hip_runtime.h>
#include <hip/hip_bf16.h>

#define T_   32
#define B_   32
#define NIN_ 512
#define H_   1024
#define NOUT_ 256
#define NBLK 64

typedef short bf16x8 __attribute__((ext_vector_type(8)));
typedef float f32x4  __attribute__((ext_vector_type(4)));
typedef float f32x8  __attribute__((ext_vector_type(8)));

__device__ __forceinline__ float bf2f(unsigned short u) {
  union { unsigned int i; float f; } x; x.i = ((unsigned int)u) << 16; return x.f;
}
__device__ __forceinline__ unsigned short f2bf(float f) {
  __hip_bfloat16 h = __float2bfloat16(f);
  return *reinterpret_cast<unsigned short*>(&h);
}
// split f32 into hi+lo bf16 (residual ~2^-18 rel)
__device__ __forceinline__ void split8(f32x8 v, bf16x8& hi, bf16x8& lo) {
#pragma unroll
  for (int i = 0; i < 8; i++) {
    unsigned short h = f2bf(v[i]);
    hi[i] = (short)h;
    lo[i] = (short)f2bf(v[i] - bf2f(h));
  }
}

// ---------- dtype detect + barrier init ----------
__global__ void init_detect(const unsigned short* __restrict__ x_raw,
                            int* __restrict__ flag, int* __restrict__ bar) {
  __shared__ int bad;
  if (threadIdx.x == 0) bad = 0;
  __syncthreads();
  int cnt = 0;
  for (int i = threadIdx.x; i < 2048; i += 256) {
    float v = bf2f(x_raw[i]);
    if (!(fabsf(v) < 1e9f)) cnt++;
  }
  if (cnt) atomicAdd(&bad, 1);
  __syncthreads();
  if (threadIdx.x == 0) {
    flag[0] = bad ? 1 : 0;  // 1 = inputs are f32
    bar[0] = 0;
    bar[1] = 0;
  }
}

// ---------- canonicalize x to f32 (exact either way) ----------
__global__ void convert_f32(const void* __restrict__ src, float* __restrict__ dst,
                            int n, const int* __restrict__ flag) {
  bool isf32 = flag[0] != 0;
  for (int i = blockIdx.x * 256 + threadIdx.x; i < n; i += gridDim.x * 256) {
    if (isf32) dst[i] = ((const float*)src)[i];
    else       dst[i] = bf2f(((const unsigned short*)src)[i]);
  }
}

// ---------- params -> float: [lam, eta, g[1024], b[1024]] ----------
__global__ void prep_params(const void* lam, const void* eta, const void* g, const void* b,
                            float* __restrict__ par, const int* __restrict__ flag) {
  bool isf32 = flag[0] != 0;
  int t = blockIdx.x * 256 + threadIdx.x;
  if (t == 0) {
    par[0] = isf32 ? ((const float*)lam)[0] : bf2f(((const unsigned short*)lam)[0]);
    par[1] = isf32 ? ((const float*)eta)[0] : bf2f(((const unsigned short*)eta)[0]);
  }
  if (t < H_) {
    par[2 + t]      = isf32 ? ((const float*)g)[t] : bf2f(((const unsigned short*)g)[t]);
    par[2 + H_ + t] = isf32 ? ((const float*)b)[t] : bf2f(((const unsigned short*)b)[t]);
  }
}

// ---------- transpose + hi/lo split: W [R][C] -> WT_hi/WT_lo bf16 [C][R] ----------
__global__ void split_transpose(const void* __restrict__ in,
                                unsigned short* __restrict__ out_hi,
                                unsigned short* __restrict__ out_lo,
                                int R, int C, const int* __restrict__ flag) {
  __shared__ unsigned short thi[32][33], tlo[32][33];
  bool isf32 = flag[0] != 0;
  int c0 = blockIdx.x * 32, r0 = blockIdx.y * 32;
  int tx = threadIdx.x & 31, ty = threadIdx.x >> 5;
  for (int i = ty; i < 32; i += 8) {
    size_t idx = (size_t)(r0 + i) * C + c0 + tx;
    float v = isf32 ? ((const float*)in)[idx] : bf2f(((const unsigned short*)in)[idx]);
    unsigned short h = f2bf(v);
    thi[i][tx] = h;
    tlo[i][tx] = f2bf(v - bf2f(h));
  }
  __syncthreads();
  for (int i = ty; i < 32; i += 8) {
    out_hi[(size_t)(c0 + i) * R + r0 + tx] = thi[tx][i];
    out_lo[(size_t)(c0 + i) * R + r0 + tx] = tlo[tx][i];
  }
}

// ---------- MFMA GEMM, near-f32 via bf16x3: C = act(act_in(A) @ B^T) ----------
// A f32 [M][K]; B pre-split hi/lo bf16 [N][K]; one 16x16 tile per wave.
template<int K, int N, int RELUA, int RELUOUT>
__global__ void gemm16_3(const float* __restrict__ A,
                         const unsigned short* __restrict__ BT_hi,
                         const unsigned short* __restrict__ BT_lo,
                         float* __restrict__ C) {
  int wave = (blockIdx.x * blockDim.x + threadIdx.x) >> 6;
  int lane = threadIdx.x & 63;
  const int ntj = N >> 4;
  int mt = wave / ntj, jt = wave - mt * ntj;
  int col = lane & 15, quad = lane >> 4;
  const float*          ap = A     + (size_t)(mt * 16 + col) * K + quad * 8;
  const unsigned short* bh = BT_hi + (size_t)(jt * 16 + col) * K + quad * 8;
  const unsigned short* bl = BT_lo + (size_t)(jt * 16 + col) * K + quad * 8;
  f32x4 acc = {0.f, 0.f, 0.f, 0.f};
#pragma unroll 4
  for (int kk = 0; kk < K; kk += 32) {
    f32x8 av = *(const f32x8*)(ap + kk);
    if (RELUA) {
#pragma unroll
      for (int i = 0; i < 8; i++) av[i] = fmaxf(av[i], 0.f);
    }
    bf16x8 ahi, alo;
    split8(av, ahi, alo);
    bf16x8 vh = *(const bf16x8*)(bh + kk);
    bf16x8 vl = *(const bf16x8*)(bl + kk);
    acc = __builtin_amdgcn_mfma_f32_16x16x32_bf16(ahi, vh, acc, 0, 0, 0);
    acc = __builtin_amdgcn_mfma_f32_16x16x32_bf16(alo, vh, acc, 0, 0, 0);
    acc = __builtin_amdgcn_mfma_f32_16x16x32_bf16(ahi, vl, acc, 0, 0, 0);
  }
#pragma unroll
  for (int r = 0; r < 4; r++) {
    float v = acc[r];
    if (RELUOUT) v = fmaxf(v, 0.f);
    C[(size_t)(mt * 16 + quad * 4 + r) * N + jt * 16 + col] = v;
  }
}

// ---------- software grid barrier (sense-reversing, device scope; proven R3) ----------
__device__ __forceinline__ void gbar(int* __restrict__ bar, int& ls) {
  __threadfence();
  __syncthreads();
  ls ^= 1;
  if (threadIdx.x == 0) {
    if (__hip_atomic_fetch_add(&bar[0], 1, __ATOMIC_ACQ_REL, __HIP_MEMORY_SCOPE_AGENT)
        == NBLK - 1) {
      __hip_atomic_store(&bar[0], 0, __ATOMIC_RELAXED, __HIP_MEMORY_SCOPE_AGENT);
      __hip_atomic_store(&bar[1], ls, __ATOMIC_RELEASE, __HIP_MEMORY_SCOPE_AGENT);
    } else {
      while (__hip_atomic_load(&bar[1], __ATOMIC_ACQUIRE, __HIP_MEMORY_SCOPE_AGENT) != ls)
        __builtin_amdgcn_s_sleep(2);
    }
  }
  __syncthreads();
  __threadfence();
}

// 16x16 tile GEMM chunk, bf16x3 (A f32, B split)
#define MFMA3_LOOP(apb, bhb, blb, accv)                                        \
  _Pragma("unroll 4")                                                          \
  for (int kk = 0; kk < H_; kk += 32) {                                        \
    f32x8 av = *(const f32x8*)((apb) + kk);                                    \
    bf16x8 ahi, alo;                                                           \
    split8(av, ahi, alo);                                                      \
    bf16x8 vh = *(const bf16x8*)((bhb) + kk);                                  \
    bf16x8 vl = *(const bf16x8*)((blb) + kk);                                  \
    accv = __builtin_amdgcn_mfma_f32_16x16x32_bf16(ahi, vh, accv, 0, 0, 0);    \
    accv = __builtin_amdgcn_mfma_f32_16x16x32_bf16(alo, vh, accv, 0, 0, 0);    \
    accv = __builtin_amdgcn_mfma_f32_16x16x32_bf16(ahi, vl, accv, 0, 0, 0);    \
  }

// ---------- recurrent kernel: f32 state, bf16x3 MFMA, software grid barrier ----------
__global__ void __launch_bounds__(256) recurrent(
    const unsigned short* __restrict__ WhT_hi, const unsigned short* __restrict__ WhT_lo,
    const unsigned short* __restrict__ WhoT_hi, const unsigned short* __restrict__ WhoT_lo,
    const unsigned short* __restrict__ WoT_hi, const unsigned short* __restrict__ WoT_lo,
    const float* __restrict__ ZC,
    float* __restrict__ hist,
    float* __restrict__ h_cur,
    float* __restrict__ dots,
    float* __restrict__ O_f,
    const float* __restrict__ par,
    void* __restrict__ y_out,
    int* __restrict__ bar,
    const int* __restrict__ flag)
{
  __shared__ float lds_hs[32][17];
  __shared__ float lds_at[32][17];
  __shared__ float lds_mu[16], lds_sc[16], lds_bt[16];

  const int tid  = threadIdx.x;
  const int wg   = blockIdx.x;
  const int wv   = tid >> 6, lane = tid & 63;
  const int gwave = wg * 4 + wv;
  const int col  = lane & 15, quad = lane >> 4;
  const float lam = par[0];
  const float eta = par[1];
  const float* g_par = par + 2;
  const float* b_par = par + 2 + H_;
  const bool isf32 = flag[0] != 0;
  int ls = 0;

  for (int i = wg * 256 + tid; i < B_ * H_; i += NBLK * 256) h_cur[i] = 0.f;
  gbar(bar, ls);

  for (int t = 0; t < T_; ++t) {
    // ---- stage 1: hist[t] = relu(zc_t + h_cur @ W_h) ----
    if (gwave < 128) {
      int bt = gwave & 1, jt = gwave >> 1;
      const float*          ap = h_cur  + (size_t)(bt * 16 + col) * H_ + quad * 8;
      const unsigned short* bh = WhT_hi + (size_t)(jt * 16 + col) * H_ + quad * 8;
      const unsigned short* bl = WhT_lo + (size_t)(jt * 16 + col) * H_ + quad * 8;
      const float* zbase = ZC + (size_t)t * B_ * H_;
      f32x4 acc;
#pragma unroll
      for (int r = 0; r < 4; r++)
        acc[r] = zbase[(size_t)(bt * 16 + quad * 4 + r) * H_ + jt * 16 + col];
      MFMA3_LOOP(ap, bh, bl, acc)
      float* hrow = hist + (size_t)t * B_ * H_;
#pragma unroll
      for (int r = 0; r < 4; r++)
        hrow[(size_t)(bt * 16 + quad * 4 + r) * H_ + jt * 16 + col] = fmaxf(acc[r], 0.f);
    }
    gbar(bar, ls);
    // ---- stage 2a: dots[t][b][s] = hist[t][b] . hist[s][b] ----
    {
      int nd = (t + 1) * B_;
      for (int d = gwave; d < nd; d += NBLK * 4) {
        int b = d / (t + 1);
        int s = d - b * (t + 1);
        const float* p1 = hist + ((size_t)t * B_ + b) * H_ + lane * 16;
        const float* p2 = hist + ((size_t)s * B_ + b) * H_ + lane * 16;
        f32x8 x0 = *(const f32x8*)p1;
        f32x8 x1 = *(const f32x8*)(p1 + 8);
        f32x8 y0 = *(const f32x8*)p2;
        f32x8 y1 = *(const f32x8*)(p2 + 8);
        float sum = 0.f;
#pragma unroll
        for (int i = 0; i < 8; i++) sum += x0[i] * y0[i] + x1[i] * y1[i];
#pragma unroll
        for (int m = 1; m < 64; m <<= 1) sum += __shfl_xor(sum, m, 64);
        if (lane == 0) dots[((size_t)t * B_ + b) * T_ + s] = sum;
      }
    }
    gbar(bar, ls);
    // ---- stage 2b: hs = hist[t]@W_h + zc + attn; batchnorm -> h_cur ----
    {
      const int j0 = wg * 16;
      if (wv < 2) {
        int b0 = wv * 16;
        const float*          ap = hist   + ((size_t)t * B_ + b0 + col) * H_ + quad * 8;
        const unsigned short* bh = WhT_hi + (size_t)(j0 + col) * H_ + quad * 8;
        const unsigned short* bl = WhT_lo + (size_t)(j0 + col) * H_ + quad * 8;
        const float* zbase = ZC + (size_t)t * B_ * H_;
        f32x4 acc;
#pragma unroll
        for (int r = 0; r < 4; r++)
          acc[r] = zbase[(size_t)(b0 + quad * 4 + r) * H_ + j0 + col];
        MFMA3_LOOP(ap, bh, bl, acc)
#pragma unroll
        for (int r = 0; r < 4; r++) lds_hs[b0 + quad * 4 + r][col] = acc[r];
      } else {
        int local = (wv - 2) * 64 + lane;  // 0..127
        int jl = local & 15;
        int bg = local >> 4;               // 0..7, 4 batches each
        float av0 = 0, av1 = 0, av2 = 0, av3 = 0;
        float w = eta;                     // eta * lam^(t-s), s = t..0
        for (int s = t; s >= 0; --s) {
          const float* dr = dots + (size_t)t * B_ * T_ + s;
          const float* hr = hist + (size_t)s * B_ * H_ + j0 + jl;
          av0 += w * dr[(bg * 4 + 0) * T_] * hr[(size_t)(bg * 4 + 0) * H_];
          av1 += w * dr[(bg * 4 + 1) * T_] * hr[(size_t)(bg * 4 + 1) * H_];
          av2 += w * dr[(bg * 4 + 2) * T_] * hr[(size_t)(bg * 4 + 2) * H_];
          av3 += w * dr[(bg * 4 + 3) * T_] * hr[(size_t)(bg * 4 + 3) * H_];
          w *= lam;
        }
        lds_at[bg * 4 + 0][jl] = av0;
        lds_at[bg * 4 + 1][jl] = av1;
        lds_at[bg * 4 + 2][jl] = av2;
        lds_at[bg * 4 + 3][jl] = av3;
      }
      __syncthreads();
      if (tid < 16) {
        float sum = 0.f;
#pragma unroll
        for (int b = 0; b < 32; b++) sum += lds_hs[b][tid] + lds_at[b][tid];
        float mu = sum * (1.f / 32.f);
        float sq = 0.f;
#pragma unroll
        for (int b = 0; b < 32; b++) {
          float d = lds_hs[b][tid] + lds_at[b][tid] - mu;
          sq += d * d;
        }
        float sig = sqrtf(sq * (1.f / 32.f));
        lds_mu[tid] = mu;
        lds_sc[tid] = g_par[j0 + tid] / sig;
        lds_bt[tid] = b_par[j0 + tid];
      }
      __syncthreads();
      for (int idx = tid; idx < 512; idx += 256) {
        int b = idx >> 4, jl = idx & 15;
        float v = lds_hs[b][jl] + lds_at[b][jl];
        v = (v - lds_mu[jl]) * lds_sc[jl] + lds_bt[jl];
        h_cur[(size_t)b * H_ + j0 + jl] = fmaxf(v, 0.f);
      }
    }
    gbar(bar, ls);
  }
  // ---- o = relu(h_cur @ W_ho) ----
  if (gwave < 128) {
    int bt = gwave & 1, jt = gwave >> 1;
    const float*          ap = h_cur   + (size_t)(bt * 16 + col) * H_ + quad * 8;
    const unsigned short* bh = WhoT_hi + (size_t)(jt * 16 + col) * H_ + quad * 8;
    const unsigned short* bl = WhoT_lo + (size_t)(jt * 16 + col) * H_ + quad * 8;
    f32x4 acc = {0.f, 0.f, 0.f, 0.f};
    MFMA3_LOOP(ap, bh, bl, acc)
#pragma unroll
    for (int r = 0; r < 4; r++)
      O_f[(size_t)(bt * 16 + quad * 4 + r) * H_ + jt * 16 + col] = fmaxf(acc[r], 0.f);
  }
  gbar(bar, ls);
  // ---- y = relu(o @ W_o), dtype per flag ----
  if (gwave < 32) {
    int bt = gwave & 1, jt = gwave >> 1;  // jt 0..15
    const float*          ap = O_f    + (size_t)(bt * 16 + col) * H_ + quad * 8;
    const unsigned short* bh = WoT_hi + (size_t)(jt * 16 + col) * H_ + quad * 8;
    const unsigned short* bl = WoT_lo + (size_t)(jt * 16 + col) * H_ + quad * 8;
    f32x4 acc = {0.f, 0.f, 0.f, 0.f};
    MFMA3_LOOP(ap, bh, bl, acc)
#pragma unroll
    for (int r = 0; r < 4; r++) {
      float v = fmaxf(acc[r], 0.f);
      size_t idx = (size_t)(bt * 16 + quad * 4 + r) * NOUT_ + jt * 16 + col;
      if (isf32) ((float*)y_out)[idx] = v;
      else       ((unsigned short*)y_out)[idx] = f2bf(v);
    }
  }
}

extern "C" void kernel_launch(void* const* d_in, const int* in_sizes, int n_in,
                              void* d_out, int out_size, void* d_ws, size_t ws_size,
                              hipStream_t stream) {
  const void* x_in = d_in[0];
  const void* W_i  = d_in[1];
  const void* W_z  = d_in[2];
  const void* W_c  = d_in[3];
  const void* W_h  = d_in[4];
  const void* W_ho = d_in[5];
  const void* W_o  = d_in[6];
  const void* lam  = d_in[7];
  const void* eta  = d_in[8];
  const void* g    = d_in[9];
  const void* bb   = d_in[10];

  char* wsp = (char*)d_ws;
  size_t off = 0;
  auto alloc = [&](size_t bytes) {
    void* p = wsp + off;
    off += (bytes + 255) & ~(size_t)255;
    return p;
  };
  int*            flag   = (int*)alloc(16);
  int*            bar    = (int*)alloc(16);
  float*          par    = (float*)alloc((2 + 2 * H_) * 4);
  float*          X_f    = (float*)alloc((size_t)T_ * B_ * NIN_ * 4);
  unsigned short* WiT_hi = (unsigned short*)alloc((size_t)NIN_ * H_ * 2);
  unsigned short* WiT_lo = (unsigned short*)alloc((size_t)NIN_ * H_ * 2);
  unsigned short* WzT_hi = (unsigned short*)alloc((size_t)H_ * H_ * 2);
  unsigned short* WzT_lo = (unsigned short*)alloc((size_t)H_ * H_ * 2);
  unsigned short* WcT_hi = (unsigned short*)alloc((size_t)H_ * H_ * 2);
  unsigned short* WcT_lo = (unsigned short*)alloc((size_t)H_ * H_ * 2);
  unsigned short* WhT_hi = (unsigned short*)alloc((size_t)H_ * H_ * 2);
  unsigned short* WhT_lo = (unsigned short*)alloc((size_t)H_ * H_ * 2);
  unsigned short* WhoT_hi= (unsigned short*)alloc((size_t)H_ * H_ * 2);
  unsigned short* WhoT_lo= (unsigned short*)alloc((size_t)H_ * H_ * 2);
  unsigned short* WoT_hi = (unsigned short*)alloc((size_t)H_ * NOUT_ * 2);
  unsigned short* WoT_lo = (unsigned short*)alloc((size_t)H_ * NOUT_ * 2);
  float*          S_f    = (float*)alloc((size_t)T_ * B_ * H_ * 4);
  float*          Z_f    = (float*)alloc((size_t)T_ * B_ * H_ * 4);
  float*          hist   = (float*)alloc((size_t)T_ * B_ * H_ * 4);
  float*          h_cur  = (float*)alloc((size_t)B_ * H_ * 4);
  float*          dots   = (float*)alloc((size_t)T_ * B_ * T_ * 4);
  float*          O_f    = (float*)alloc((size_t)B_ * H_ * 4);
  float*          ZC     = S_f;  // S dead after Z computed
  (void)ws_size; (void)in_sizes; (void)n_in; (void)out_size;

  // 1. detect dtype + init barrier; canonicalize x; params
  init_detect<<<1, 256, 0, stream>>>((const unsigned short*)x_in, flag, bar);
  convert_f32<<<256, 256, 0, stream>>>(x_in, X_f, T_ * B_ * NIN_, flag);
  prep_params<<<4, 256, 0, stream>>>(lam, eta, g, bb, par, flag);

  // 2. transpose + hi/lo split all weights -> bf16 [N][K]
  split_transpose<<<dim3(H_ / 32, NIN_ / 32), 256, 0, stream>>>(W_i, WiT_hi, WiT_lo, NIN_, H_, flag);
  split_transpose<<<dim3(H_ / 32, H_ / 32), 256, 0, stream>>>(W_z, WzT_hi, WzT_lo, H_, H_, flag);
  split_transpose<<<dim3(H_ / 32, H_ / 32), 256, 0, stream>>>(W_c, WcT_hi, WcT_lo, H_, H_, flag);
  split_transpose<<<dim3(H_ / 32, H_ / 32), 256, 0, stream>>>(W_h, WhT_hi, WhT_lo, H_, H_, flag);
  split_transpose<<<dim3(H_ / 32, H_ / 32), 256, 0, stream>>>(W_ho, WhoT_hi, WhoT_lo, H_, H_, flag);
  split_transpose<<<dim3(NOUT_ / 32, H_ / 32), 256, 0, stream>>>(W_o, WoT_hi, WoT_lo, H_, NOUT_, flag);

  // 3. phase A (carry-independent), bf16x3 MFMA:
  //    S = relu(relu(X)@W_i); Z = relu(S@W_z); ZC = Z@W_c
  gemm16_3<NIN_, H_, 1, 1><<<1024, 256, 0, stream>>>(X_f, WiT_hi, WiT_lo, S_f);
  gemm16_3<H_,   H_, 0, 1><<<1024, 256, 0, stream>>>(S_f, WzT_hi, WzT_lo, Z_f);
  gemm16_3<H_,   H_, 0, 0><<<1024, 256, 0, stream>>>(Z_f, WcT_hi, WcT_lo, ZC);

  // 4. phase B: recurrence + readout in ONE kernel (software grid barrier)
  recurrent<<<NBLK, 256, 0, stream>>>(WhT_hi, WhT_lo, WhoT_hi, WhoT_lo, WoT_hi, WoT_lo,
                                      ZC, hist, h_cur, dots, O_f, par, d_out, bar, flag);
}

// Round 7
// 2322.448 us; speedup vs baseline: 1.1868x; 1.1868x over previous
//
#include <hip/hip_runtime.h>
#include <hip/hip_bf16.h>

#define T_   32
#define B_   32
#define NIN_ 512
#define H_   1024
#define NOUT_ 256
#define NBLK 32
#define NCOL 32   // columns owned per block
#define NSLOT 96

typedef short bf16x8 __attribute__((ext_vector_type(8)));
typedef float f32x4  __attribute__((ext_vector_type(4)));
typedef float f32x8  __attribute__((ext_vector_type(8)));

__device__ __forceinline__ float bf2f(unsigned short u) {
  union { unsigned int i; float f; } x; x.i = ((unsigned int)u) << 16; return x.f;
}
__device__ __forceinline__ unsigned short f2bf(float f) {
  __hip_bfloat16 h = __float2bfloat16(f);
  return *reinterpret_cast<unsigned short*>(&h);
}
__device__ __forceinline__ void split8(f32x8 v, bf16x8& hi, bf16x8& lo) {
#pragma unroll
  for (int i = 0; i < 8; i++) {
    unsigned short h = f2bf(v[i]);
    hi[i] = (short)h;
    lo[i] = (short)f2bf(v[i] - bf2f(h));
  }
}

// ---- coherent (cache-bypassing) primitives: relaxed agent-scope atomics ----
__device__ __forceinline__ float ald(const float* p) {
  return __hip_atomic_load((float*)p, __ATOMIC_RELAXED, __HIP_MEMORY_SCOPE_AGENT);
}
__device__ __forceinline__ void ast(float* p, float v) {
  __hip_atomic_store(p, v, __ATOMIC_RELAXED, __HIP_MEMORY_SCOPE_AGENT);
}
__device__ __forceinline__ void aadd(float* p, float v) {
  __hip_atomic_fetch_add(p, v, __ATOMIC_RELAXED, __HIP_MEMORY_SCOPE_AGENT);
}
__device__ __forceinline__ f32x8 coh_load8(const float* p) {
  const unsigned long long* q = (const unsigned long long*)p;
  f32x8 r;
#pragma unroll
  for (int i = 0; i < 4; i++) {
    unsigned long long v =
        __hip_atomic_load((unsigned long long*)(q + i), __ATOMIC_RELAXED,
                          __HIP_MEMORY_SCOPE_AGENT);
    union { unsigned long long u; float f[2]; } c; c.u = v;
    r[2 * i] = c.f[0]; r[2 * i + 1] = c.f[1];
  }
  return r;
}

// ---- rendezvous: fresh slot per use; release add, RELAXED spin (no L2 inv) ----
__device__ __forceinline__ void rendezvous(int* cnt, int slot) {
  __syncthreads();  // drains each wave's vmcnt -> all prior atomics complete
  if (threadIdx.x == 0) {
    __hip_atomic_fetch_add(&cnt[slot], 1, __ATOMIC_RELEASE, __HIP_MEMORY_SCOPE_AGENT);
    while (__hip_atomic_load(&cnt[slot], __ATOMIC_RELAXED, __HIP_MEMORY_SCOPE_AGENT) < NBLK)
      __builtin_amdgcn_s_sleep(4);
    __atomic_signal_fence(__ATOMIC_ACQUIRE);
  }
  __syncthreads();
}

// ---------- dtype detect + counter init ----------
__global__ void init_detect(const unsigned short* __restrict__ x_raw,
                            int* __restrict__ flag, int* __restrict__ cnt) {
  __shared__ int bad;
  if (threadIdx.x == 0) bad = 0;
  __syncthreads();
  int c = 0;
  for (int i = threadIdx.x; i < 2048; i += 256) {
    float v = bf2f(x_raw[i]);
    if (!(fabsf(v) < 1e9f)) c++;
  }
  if (c) atomicAdd(&bad, 1);
  __syncthreads();
  if (threadIdx.x == 0) flag[0] = bad ? 1 : 0;  // 1 = inputs are f32
  for (int i = threadIdx.x; i < NSLOT; i += 256)
    __hip_atomic_store(&cnt[i], 0, __ATOMIC_RELAXED, __HIP_MEMORY_SCOPE_AGENT);
}

// ---------- canonicalize x to f32 (exact either way) ----------
__global__ void convert_f32(const void* __restrict__ src, float* __restrict__ dst,
                            int n, const int* __restrict__ flag) {
  bool isf32 = flag[0] != 0;
  for (int i = blockIdx.x * 256 + threadIdx.x; i < n; i += gridDim.x * 256) {
    if (isf32) dst[i] = ((const float*)src)[i];
    else       dst[i] = bf2f(((const unsigned short*)src)[i]);
  }
}

// ---------- params -> float: [lam, eta, g[1024], b[1024]] ----------
__global__ void prep_params(const void* lam, const void* eta, const void* g, const void* b,
                            float* __restrict__ par, const int* __restrict__ flag) {
  bool isf32 = flag[0] != 0;
  int t = blockIdx.x * 256 + threadIdx.x;
  if (t == 0) {
    par[0] = isf32 ? ((const float*)lam)[0] : bf2f(((const unsigned short*)lam)[0]);
    par[1] = isf32 ? ((const float*)eta)[0] : bf2f(((const unsigned short*)eta)[0]);
  }
  if (t < H_) {
    par[2 + t]      = isf32 ? ((const float*)g)[t] : bf2f(((const unsigned short*)g)[t]);
    par[2 + H_ + t] = isf32 ? ((const float*)b)[t] : bf2f(((const unsigned short*)b)[t]);
  }
}

// ---------- transpose + hi/lo split: W [R][C] -> bf16 [C][R] ----------
__global__ void split_transpose(const void* __restrict__ in,
                                unsigned short* __restrict__ out_hi,
                                unsigned short* __restrict__ out_lo,
                                int R, int C, const int* __restrict__ flag) {
  __shared__ unsigned short thi[32][33], tlo[32][33];
  bool isf32 = flag[0] != 0;
  int c0 = blockIdx.x * 32, r0 = blockIdx.y * 32;
  int tx = threadIdx.x & 31, ty = threadIdx.x >> 5;
  for (int i = ty; i < 32; i += 8) {
    size_t idx = (size_t)(r0 + i) * C + c0 + tx;
    float v = isf32 ? ((const float*)in)[idx] : bf2f(((const unsigned short*)in)[idx]);
    unsigned short h = f2bf(v);
    thi[i][tx] = h;
    tlo[i][tx] = f2bf(v - bf2f(h));
  }
  __syncthreads();
  for (int i = ty; i < 32; i += 8) {
    out_hi[(size_t)(c0 + i) * R + r0 + tx] = thi[tx][i];
    out_lo[(size_t)(c0 + i) * R + r0 + tx] = tlo[tx][i];
  }
}

// ---------- MFMA GEMM (phase A), bf16x3: C = act(act_in(A) @ B^T) ----------
template<int K, int N, int RELUA, int RELUOUT>
__global__ void gemm16_3(const float* __restrict__ A,
                         const unsigned short* __restrict__ BT_hi,
                         const unsigned short* __restrict__ BT_lo,
                         float* __restrict__ C) {
  int wave = (blockIdx.x * blockDim.x + threadIdx.x) >> 6;
  int lane = threadIdx.x & 63;
  const int ntj = N >> 4;
  int mt = wave / ntj, jt = wave - mt * ntj;
  int col = lane & 15, quad = lane >> 4;
  const float*          ap = A     + (size_t)(mt * 16 + col) * K + quad * 8;
  const unsigned short* bh = BT_hi + (size_t)(jt * 16 + col) * K + quad * 8;
  const unsigned short* bl = BT_lo + (size_t)(jt * 16 + col) * K + quad * 8;
  f32x4 acc = {0.f, 0.f, 0.f, 0.f};
#pragma unroll 4
  for (int kk = 0; kk < K; kk += 32) {
    f32x8 av = *(const f32x8*)(ap + kk);
    if (RELUA) {
#pragma unroll
      for (int i = 0; i < 8; i++) av[i] = fmaxf(av[i], 0.f);
    }
    bf16x8 ahi, alo;
    split8(av, ahi, alo);
    bf16x8 vh = *(const bf16x8*)(bh + kk);
    bf16x8 vl = *(const bf16x8*)(bl + kk);
    acc = __builtin_amdgcn_mfma_f32_16x16x32_bf16(ahi, vh, acc, 0, 0, 0);
    acc = __builtin_amdgcn_mfma_f32_16x16x32_bf16(alo, vh, acc, 0, 0, 0);
    acc = __builtin_amdgcn_mfma_f32_16x16x32_bf16(ahi, vl, acc, 0, 0, 0);
  }
#pragma unroll
  for (int r = 0; r < 4; r++) {
    float v = acc[r];
    if (RELUOUT) v = fmaxf(v, 0.f);
    C[(size_t)(mt * 16 + quad * 4 + r) * N + jt * 16 + col] = v;
  }
}

// ---- one 16x16 MFMA tile, A (f32, row stride H_) read via coherent loads ----
__device__ __forceinline__ f32x4 mm_tile_coh(
    const float* __restrict__ A, int am0,
    const unsigned short* __restrict__ BH, const unsigned short* __restrict__ BL,
    int bj0, f32x4 acc, int col, int quad) {
  const float*          ap = A  + (size_t)(am0 + col) * H_ + quad * 8;
  const unsigned short* bh = BH + (size_t)(bj0 + col) * H_ + quad * 8;
  const unsigned short* bl = BL + (size_t)(bj0 + col) * H_ + quad * 8;
#pragma unroll 2
  for (int kk = 0; kk < H_; kk += 32) {
    f32x8 av = coh_load8(ap + kk);
    bf16x8 ahi, alo;
    split8(av, ahi, alo);
    bf16x8 vh = *(const bf16x8*)(bh + kk);
    bf16x8 vl = *(const bf16x8*)(bl + kk);
    acc = __builtin_amdgcn_mfma_f32_16x16x32_bf16(ahi, vh, acc, 0, 0, 0);
    acc = __builtin_amdgcn_mfma_f32_16x16x32_bf16(alo, vh, acc, 0, 0, 0);
    acc = __builtin_amdgcn_mfma_f32_16x16x32_bf16(ahi, vl, acc, 0, 0, 0);
  }
  return acc;
}

// ---------- recurrent: 32 blocks x 32 columns, coherence-free communication ----------
__global__ void __launch_bounds__(256) recurrent(
    const unsigned short* __restrict__ WhT_hi, const unsigned short* __restrict__ WhT_lo,
    const unsigned short* __restrict__ WhoT_hi, const unsigned short* __restrict__ WhoT_lo,
    const unsigned short* __restrict__ WoT_hi, const unsigned short* __restrict__ WoT_lo,
    const float* __restrict__ ZC,
    float* __restrict__ h_cur,     // [B][H]  coherent
    float* __restrict__ h_pub,     // [B][H]  coherent (current h_t)
    float* __restrict__ O_pub,     // [B][H]  coherent
    float* __restrict__ hist_loc,  // [NBLK][T][B][NCOL] block-private, normal cached
    float* __restrict__ dots_g,    // [T][B][T] coherent (atomicAdd)
    const float* __restrict__ par,
    void* __restrict__ y_out,
    int* __restrict__ cnt,
    const int* __restrict__ flag)
{
  __shared__ float lds_hs[B_][NCOL + 1];
  __shared__ float lds_dt[B_][T_];
  __shared__ float lds_mu[NCOL], lds_sc[NCOL], lds_bb[NCOL];

  const int tid = threadIdx.x, wg = blockIdx.x;
  const int wv = tid >> 6, lane = tid & 63;
  const int col = lane & 15, quad = lane >> 4;
  const int j0 = wg * NCOL;
  const int bt = wv >> 1, jtl = wv & 1;   // this wave's tile: batch-half x col-half
  const int am0 = bt * 16;
  const int cl0 = jtl * 16;
  const int jg0 = j0 + cl0;
  const float lam = par[0], eta = par[1];
  const bool isf32 = flag[0] != 0;
  float* hl = hist_loc + (size_t)wg * (T_ * B_ * NCOL);

  // zero h_cur (batch row wg) and this block's dots_g slice
  for (int i = tid; i < H_; i += 256) ast(h_cur + (size_t)wg * H_ + i, 0.f);
  {
    const int per = T_ * B_ * T_ / NBLK;  // 1024
    for (int i = tid; i < per; i += 256) ast(dots_g + (size_t)wg * per + i, 0.f);
  }
  rendezvous(cnt, 0);

  int slot = 1;
  for (int t = 0; t < T_; ++t) {
    const float* zb = ZC + (size_t)t * B_ * H_;
    // ---- stage 1: h_t tile = relu(zc + h_cur @ W_h) ----
    {
      f32x4 acc;
#pragma unroll
      for (int r = 0; r < 4; r++)
        acc[r] = zb[(size_t)(am0 + quad * 4 + r) * H_ + jg0 + col];
      acc = mm_tile_coh(h_cur, am0, WhT_hi, WhT_lo, jg0, acc, col, quad);
#pragma unroll
      for (int r = 0; r < 4; r++) {
        float v = fmaxf(acc[r], 0.f);
        int m = am0 + quad * 4 + r;
        ast(h_pub + (size_t)m * H_ + jg0 + col, v);            // publish (coherent)
        hl[((size_t)t * B_ + m) * NCOL + cl0 + col] = v;       // private history
      }
    }
    __syncthreads();
    // ---- partial dots over own columns -> atomicAdd ----
    for (int d = tid; d < B_ * (t + 1); d += 256) {
      int b = d / (t + 1), s = d - b * (t + 1);
      const f32x4* p = (const f32x4*)(hl + ((size_t)t * B_ + b) * NCOL);
      const f32x4* q = (const f32x4*)(hl + ((size_t)s * B_ + b) * NCOL);
      float sum = 0.f;
#pragma unroll
      for (int i = 0; i < 8; i++) {
        f32x4 a = p[i], c = q[i];
        sum += a[0] * c[0] + a[1] * c[1] + a[2] * c[2] + a[3] * c[3];
      }
      aadd(dots_g + ((size_t)t * B_ + b) * T_ + s, sum);
    }
    rendezvous(cnt, slot++);
    // ---- stage full dots row into LDS ----
    for (int d = tid; d < B_ * (t + 1); d += 256) {
      int b = d / (t + 1), s = d - b * (t + 1);
      lds_dt[b][s] = ald(dots_g + ((size_t)t * B_ + b) * T_ + s);
    }
    // ---- hs GEMM tile: h_t @ W_h + zc ----
    {
      f32x4 acc;
#pragma unroll
      for (int r = 0; r < 4; r++)
        acc[r] = zb[(size_t)(am0 + quad * 4 + r) * H_ + jg0 + col];
      acc = mm_tile_coh(h_pub, am0, WhT_hi, WhT_lo, jg0, acc, col, quad);
#pragma unroll
      for (int r = 0; r < 4; r++) lds_hs[am0 + quad * 4 + r][cl0 + col] = acc[r];
    }
    __syncthreads();
    // ---- attention: += eta * sum_s lam^(t-s) dots[b][s] * hl[s][b][c] ----
    for (int d = tid; d < B_ * NCOL; d += 256) {
      int b = d >> 5, c = d & 31;
      float a = 0.f, w = eta;
      const float* hb = hl + (size_t)b * NCOL + c;
      for (int s = t; s >= 0; --s) {
        a += w * lds_dt[b][s] * hb[(size_t)s * B_ * NCOL];
        w *= lam;
      }
      lds_hs[b][c] += a;
    }
    __syncthreads();
    // ---- batch-norm (block-local: all batches of own columns) ----
    if (tid < NCOL) {
      int c = tid;
      float sum = 0.f;
#pragma unroll
      for (int b = 0; b < B_; b++) sum += lds_hs[b][c];
      float mu = sum * (1.f / B_);
      float sq = 0.f;
#pragma unroll
      for (int b = 0; b < B_; b++) {
        float dd = lds_hs[b][c] - mu;
        sq += dd * dd;
      }
      float sig = sqrtf(sq * (1.f / B_));
      lds_mu[c] = mu;
      lds_sc[c] = par[2 + j0 + c] / sig;
      lds_bb[c] = par[2 + H_ + j0 + c];
    }
    __syncthreads();
    // ---- apply + publish h_cur slice ----
    for (int d = tid; d < B_ * NCOL; d += 256) {
      int b = d >> 5, c = d & 31;
      float v = (lds_hs[b][c] - lds_mu[c]) * lds_sc[c] + lds_bb[c];
      ast(h_cur + (size_t)b * H_ + j0 + c, fmaxf(v, 0.f));
    }
    rendezvous(cnt, slot++);
  }
  // ---- o = relu(h_cur @ W_ho) (own columns) ----
  {
    f32x4 acc = {0.f, 0.f, 0.f, 0.f};
    acc = mm_tile_coh(h_cur, am0, WhoT_hi, WhoT_lo, jg0, acc, col, quad);
#pragma unroll
    for (int r = 0; r < 4; r++)
      ast(O_pub + (size_t)(am0 + quad * 4 + r) * H_ + jg0 + col, fmaxf(acc[r], 0.f));
  }
  rendezvous(cnt, slot++);
  // ---- y = relu(o @ W_o): 32 tiles on blocks 0..7 ----
  if (wg < 8) {
    int id = wg * 4 + wv;          // 0..31
    int bt2 = id & 1, jt2 = id >> 1;  // jt2 0..15
    f32x4 acc = {0.f, 0.f, 0.f, 0.f};
    acc = mm_tile_coh(O_pub, bt2 * 16, WoT_hi, WoT_lo, jt2 * 16, acc, col, quad);
#pragma unroll
    for (int r = 0; r < 4; r++) {
      float v = fmaxf(acc[r], 0.f);
      size_t idx = (size_t)(bt2 * 16 + quad * 4 + r) * NOUT_ + jt2 * 16 + col;
      if (isf32) ((float*)y_out)[idx] = v;
      else       ((unsigned short*)y_out)[idx] = f2bf(v);
    }
  }
}

extern "C" void kernel_launch(void* const* d_in, const int* in_sizes, int n_in,
                              void* d_out, int out_size, void* d_ws, size_t ws_size,
                              hipStream_t stream) {
  const void* x_in = d_in[0];
  const void* W_i  = d_in[1];
  const void* W_z  = d_in[2];
  const void* W_c  = d_in[3];
  const void* W_h  = d_in[4];
  const void* W_ho = d_in[5];
  const void* W_o  = d_in[6];
  const void* lam  = d_in[7];
  const void* eta  = d_in[8];
  const void* g    = d_in[9];
  const void* bb   = d_in[10];

  char* wsp = (char*)d_ws;
  size_t off = 0;
  auto alloc = [&](size_t bytes) {
    void* p = wsp + off;
    off += (bytes + 255) & ~(size_t)255;
    return p;
  };
  int*            flag    = (int*)alloc(16);
  int*            cnt     = (int*)alloc(NSLOT * 4);
  float*          par     = (float*)alloc((2 + 2 * H_) * 4);
  float*          X_f     = (float*)alloc((size_t)T_ * B_ * NIN_ * 4);
  unsigned short* WiT_hi  = (unsigned short*)alloc((size_t)NIN_ * H_ * 2);
  unsigned short* WiT_lo  = (unsigned short*)alloc((size_t)NIN_ * H_ * 2);
  unsigned short* WzT_hi  = (unsigned short*)alloc((size_t)H_ * H_ * 2);
  unsigned short* WzT_lo  = (unsigned short*)alloc((size_t)H_ * H_ * 2);
  unsigned short* WcT_hi  = (unsigned short*)alloc((size_t)H_ * H_ * 2);
  unsigned short* WcT_lo  = (unsigned short*)alloc((size_t)H_ * H_ * 2);
  unsigned short* WhT_hi  = (unsigned short*)alloc((size_t)H_ * H_ * 2);
  unsigned short* WhT_lo  = (unsigned short*)alloc((size_t)H_ * H_ * 2);
  unsigned short* WhoT_hi = (unsigned short*)alloc((size_t)H_ * H_ * 2);
  unsigned short* WhoT_lo = (unsigned short*)alloc((size_t)H_ * H_ * 2);
  unsigned short* WoT_hi  = (unsigned short*)alloc((size_t)H_ * NOUT_ * 2);
  unsigned short* WoT_lo  = (unsigned short*)alloc((size_t)H_ * NOUT_ * 2);
  float*          S_f     = (float*)alloc((size_t)T_ * B_ * H_ * 4);
  float*          Z_f     = (float*)alloc((size_t)T_ * B_ * H_ * 4);
  float*          h_cur   = (float*)alloc((size_t)B_ * H_ * 4);
  float*          h_pub   = (float*)alloc((size_t)B_ * H_ * 4);
  float*          O_pub   = (float*)alloc((size_t)B_ * H_ * 4);
  float*          histloc = (float*)alloc((size_t)NBLK * T_ * B_ * NCOL * 4);
  float*          dots_g  = (float*)alloc((size_t)T_ * B_ * T_ * 4);
  float*          ZC      = S_f;  // S dead after Z computed
  (void)ws_size; (void)in_sizes; (void)n_in; (void)out_size;

  // 1. detect dtype + zero rendezvous counters; canonicalize x; params
  init_detect<<<1, 256, 0, stream>>>((const unsigned short*)x_in, flag, cnt);
  convert_f32<<<256, 256, 0, stream>>>(x_in, X_f, T_ * B_ * NIN_, flag);
  prep_params<<<4, 256, 0, stream>>>(lam, eta, g, bb, par, flag);

  // 2. transpose + hi/lo split weights -> bf16 [N][K]
  split_transpose<<<dim3(H_ / 32, NIN_ / 32), 256, 0, stream>>>(W_i, WiT_hi, WiT_lo, NIN_, H_, flag);
  split_transpose<<<dim3(H_ / 32, H_ / 32), 256, 0, stream>>>(W_z, WzT_hi, WzT_lo, H_, H_, flag);
  split_transpose<<<dim3(H_ / 32, H_ / 32), 256, 0, stream>>>(W_c, WcT_hi, WcT_lo, H_, H_, flag);
  split_transpose<<<dim3(H_ / 32, H_ / 32), 256, 0, stream>>>(W_h, WhT_hi, WhT_lo, H_, H_, flag);
  split_transpose<<<dim3(H_ / 32, H_ / 32), 256, 0, stream>>>(W_ho, WhoT_hi, WhoT_lo, H_, H_, flag);
  split_transpose<<<dim3(NOUT_ / 32, H_ / 32), 256, 0, stream>>>(W_o, WoT_hi, WoT_lo, H_, NOUT_, flag);

  // 3. phase A (carry-independent): S = relu(relu(X)@W_i); Z = relu(S@W_z); ZC = Z@W_c
  gemm16_3<NIN_, H_, 1, 1><<<1024, 256, 0, stream>>>(X_f, WiT_hi, WiT_lo, S_f);
  gemm16_3<H_,   H_, 0, 1><<<1024, 256, 0, stream>>>(S_f, WzT_hi, WzT_lo, Z_f);
  gemm16_3<H_,   H_, 0, 0><<<1024, 256, 0, stream>>>(Z_f, WcT_hi, WcT_lo, ZC);

  // 4. phase B: recurrence + readout, coherence-free single kernel
  recurrent<<<NBLK, 256, 0, stream>>>(WhT_hi, WhT_lo, WhoT_hi, WhoT_lo, WoT_hi, WoT_lo,
                                      ZC, h_cur, h_pub, O_pub, histloc, dots_g,
                                      par, d_out, cnt, flag);
}